// Round 1
// baseline (1072.177 us; speedup 1.0000x reference)
//
#include <hip/hip_runtime.h>
#include <hip/hip_bf16.h>

#define RPB 256   // rows per block in tiled GEMM

// ---------------------------------------------------------------------------
// Tiled row-blocked GEMM: out[n, COLS] = f(X[n, K]) @ W[K, COLS] (+ bias)
// Thread layout: 256 threads = 8 col-groups (cg) x 32 row-groups (rg).
// Each thread: 8 rows (strided: row_l = r*32+rg) x CPT=COLS/8 cols.
// LDS strides 36 (X tile) / 33 (W^T tile) spread banks.
// CLASSIFY variant fuses: + nfw + bg, relu, 32->32 relu MLP, 32->2, softmax.
// ---------------------------------------------------------------------------
template<int COLS, int K, bool CLASSIFY>
__global__ __launch_bounds__(256) void gemm_k(
    const float* __restrict__ X, const float* __restrict__ W,
    const float* __restrict__ bias, float* __restrict__ out,
    int nrows, float scale, int relu_in,
    const float* __restrict__ nfw, const float* __restrict__ bg,
    const float* __restrict__ Wc1, const float* __restrict__ bc1,
    const float* __restrict__ Wc2, const float* __restrict__ bc2)
{
    constexpr int CPT = COLS / 8;   // cols per thread (4 or 8)
    constexpr int KT  = 32;         // k tile
    constexpr int NKT = K / KT;

    __shared__ float sx[RPB * 36];          // X tile, stride 36 words
    __shared__ float sWT[COLS * 33];        // W^T tile, stride 33 words
    __shared__ float sWc1T[CLASSIFY ? 1024 : 1];
    __shared__ float sWc2[CLASSIFY ? 64 : 1];
    __shared__ float sb[CLASSIFY ? 66 : 1]; // [0:32)=bc1 [32:64)=bg [64:66)=bc2

    const int tid = threadIdx.x;
    const int cg  = tid & 7;        // 0..7
    const int rg  = tid >> 3;       // 0..31
    const int r0  = blockIdx.x * RPB;

    if (CLASSIFY) {
        for (int i = tid; i < 1024; i += 256) {
            // Wc1 row-major [32 in][32 out] -> sWc1T[j_out*32 + i_in]
            sWc1T[(i & 31) * 32 + (i >> 5)] = Wc1[i];
        }
        if (tid < 32)                sb[tid] = bc1[tid];
        else if (tid < 64)           sb[tid] = bg[tid - 32];
        else if (tid < 66)           sb[tid] = bc2[tid - 64];
        if (tid < 64)                sWc2[tid] = Wc2[tid];
    }

    float acc[8][CPT];
    #pragma unroll
    for (int r = 0; r < 8; ++r)
        #pragma unroll
        for (int c = 0; c < CPT; ++c) acc[r][c] = 0.f;

    for (int kt = 0; kt < NKT; ++kt) {
        // ---- stage X tile: 256 rows x 32 k, as float4 ----
        #pragma unroll
        for (int j = 0; j < 8; ++j) {
            int i  = tid + j * 256;        // 0..2047
            int r  = i >> 3;
            int k4 = i & 7;
            int gr = r0 + r; if (gr >= nrows) gr = nrows - 1;
            float4 v = *(const float4*)&X[(size_t)gr * K + kt * KT + k4 * 4];
            if (relu_in) {
                v.x = fmaxf(v.x, 0.f); v.y = fmaxf(v.y, 0.f);
                v.z = fmaxf(v.z, 0.f); v.w = fmaxf(v.w, 0.f);
            }
            if (scale != 1.f) { v.x *= scale; v.y *= scale; v.z *= scale; v.w *= scale; }
            *(float4*)&sx[r * 36 + k4 * 4] = v;
        }
        // ---- stage W^T tile: COLS x 32 ----
        for (int i = tid; i < COLS * KT; i += 256) {
            int kl = i / COLS, c = i % COLS;
            sWT[c * 33 + kl] = W[(size_t)(kt * KT + kl) * COLS + c];
        }
        __syncthreads();

        #pragma unroll
        for (int k4 = 0; k4 < 8; ++k4) {
            float4 a[8];
            #pragma unroll
            for (int r = 0; r < 8; ++r)
                a[r] = *(const float4*)&sx[(r * 32 + rg) * 36 + k4 * 4];
            #pragma unroll
            for (int cc = 0; cc < CPT; ++cc) {
                int c = cg * CPT + cc;
                float w0 = sWT[c * 33 + k4 * 4 + 0];
                float w1 = sWT[c * 33 + k4 * 4 + 1];
                float w2 = sWT[c * 33 + k4 * 4 + 2];
                float w3 = sWT[c * 33 + k4 * 4 + 3];
                #pragma unroll
                for (int r = 0; r < 8; ++r)
                    acc[r][cc] += a[r].x * w0 + a[r].y * w1 + a[r].z * w2 + a[r].w * w3;
            }
        }
        __syncthreads();
    }

    if (!CLASSIFY) {
        #pragma unroll
        for (int r = 0; r < 8; ++r) {
            int row = r0 + r * 32 + rg;
            if (row < nrows) {
                #pragma unroll
                for (int cc4 = 0; cc4 < CPT / 4; ++cc4) {
                    int c = cg * CPT + cc4 * 4;
                    float4 o;
                    o.x = acc[r][cc4 * 4 + 0] + (bias ? bias[c + 0] : 0.f);
                    o.y = acc[r][cc4 * 4 + 1] + (bias ? bias[c + 1] : 0.f);
                    o.z = acc[r][cc4 * 4 + 2] + (bias ? bias[c + 2] : 0.f);
                    o.w = acc[r][cc4 * 4 + 3] + (bias ? bias[c + 3] : 0.f);
                    *(float4*)&out[(size_t)row * COLS + c] = o;
                }
            }
        }
    } else {
        // shared = relu(Tacc + nfw + bg) -> stage into sx (re-used) -> classifier
        __syncthreads();   // everyone done reading sx
        #pragma unroll
        for (int r = 0; r < 8; ++r) {
            int row = r0 + r * 32 + rg;
            int rl  = r * 32 + rg;
            float4 nf4 = make_float4(0.f, 0.f, 0.f, 0.f);
            if (row < nrows) nf4 = *(const float4*)&nfw[(size_t)row * 32 + cg * 4];
            int c = cg * 4;
            float4 o;
            o.x = fmaxf(acc[r][0] + nf4.x + sb[32 + c + 0], 0.f);
            o.y = fmaxf(acc[r][1] + nf4.y + sb[32 + c + 1], 0.f);
            o.z = fmaxf(acc[r][2] + nf4.z + sb[32 + c + 2], 0.f);
            o.w = fmaxf(acc[r][3] + nf4.w + sb[32 + c + 3], 0.f);
            *(float4*)&sx[rl * 36 + c] = o;
        }
        __syncthreads();
        // one thread per row: 32->32 relu -> 32->2 -> softmax
        int rl  = tid;
        int row = r0 + rl;
        float4 sh4[8];
        #pragma unroll
        for (int i4 = 0; i4 < 8; ++i4)
            sh4[i4] = *(const float4*)&sx[rl * 36 + i4 * 4];
        float l0 = sb[64], l1 = sb[65];
        #pragma unroll
        for (int jj = 0; jj < 32; ++jj) {
            float s = sb[jj];
            #pragma unroll
            for (int i4 = 0; i4 < 8; ++i4) {
                float4 w4 = *(const float4*)&sWc1T[jj * 32 + i4 * 4];
                s += sh4[i4].x * w4.x + sh4[i4].y * w4.y
                   + sh4[i4].z * w4.z + sh4[i4].w * w4.w;
            }
            s = fmaxf(s, 0.f);
            l0 += s * sWc2[jj * 2 + 0];
            l1 += s * sWc2[jj * 2 + 1];
        }
        if (row < nrows) {
            float p0 = 1.f / (1.f + expf(l1 - l0));
            float p1 = 1.f / (1.f + expf(l0 - l1));
            *(float2*)&out[(size_t)row * 2] = make_float2(p0, p1);
        }
    }
}

// ---------------------------------------------------------------------------
// Scatter, 64 features: one wave per edge, lane = feature.
// acc[dst, lane] += hp[src, lane] * w   (f32 atomics, device scope)
// ---------------------------------------------------------------------------
__global__ void scatter64_k(const float* __restrict__ hp,
                            const int* __restrict__ src, const int* __restrict__ dst,
                            const float* __restrict__ ew, float* __restrict__ acc,
                            int nEdges)
{
    int lane = threadIdx.x & 63;
    int wid  = (blockIdx.x * blockDim.x + threadIdx.x) >> 6;
    int nw   = (gridDim.x * blockDim.x) >> 6;
    int per  = (nEdges + nw - 1) / nw;
    int e0   = wid * per;
    int e1   = e0 + per; if (e1 > nEdges) e1 = nEdges;
    for (int e = e0; e < e1; ++e) {
        int s = src[e], d = dst[e];
        float w = ew[e];
        float v = hp[s * 64 + lane] * w;
        atomicAdd(&acc[d * 64 + lane], v);
    }
}

// ---------------------------------------------------------------------------
// Scatter, 32 features: wave = 2 edges (half = lane>>5), lane&31 = feature.
// ---------------------------------------------------------------------------
template<bool WEIGHTED, bool RELU>
__global__ void scatter32_k(const float* __restrict__ hp,
                            const int* __restrict__ src, const int* __restrict__ dst,
                            const float* __restrict__ ew, float* __restrict__ acc,
                            int nEdges)
{
    int lane = threadIdx.x & 63;
    int half = lane >> 5, c = lane & 31;
    int wid  = (blockIdx.x * blockDim.x + threadIdx.x) >> 6;
    int nw   = (gridDim.x * blockDim.x) >> 6;
    int nPairs = (nEdges + 1) >> 1;
    int per  = (nPairs + nw - 1) / nw;
    int p0   = wid * per;
    int p1   = p0 + per; if (p1 > nPairs) p1 = nPairs;
    for (int p = p0; p < p1; ++p) {
        int e = p * 2 + half;
        if (e < nEdges) {
            int s = src[e], d = dst[e];
            float v = hp[s * 32 + c];
            if (RELU)     v = fmaxf(v, 0.f);
            if (WEIGHTED) v *= ew[e];
            atomicAdd(&acc[d * 32 + c], v);
        }
    }
}

// ---------------------------------------------------------------------------
// tmp[1024,32] = edge_features[1024,64] @ We[64,32]
// ---------------------------------------------------------------------------
__global__ void efwe_k(const float* __restrict__ ef, const float* __restrict__ We,
                       float* __restrict__ tmp)
{
    int idx = blockIdx.x * 256 + threadIdx.x;   // 32768 total
    int row = idx >> 5, c = idx & 31;
    float s = 0.f;
    #pragma unroll
    for (int k = 0; k < 64; ++k)
        s += ef[row * 64 + k] * We[k * 32 + c];
    tmp[row * 32 + c] = s;
}

// ---------------------------------------------------------------------------
// edge_h[1024,32] += adj_e[1024,1024] @ tmp[1024,32], k split 4 ways (atomics).
// grid = 512: blockIdx = rowblk*4 + kq. edge_h must be pre-zeroed.
// ---------------------------------------------------------------------------
__global__ void adjmm_k(const float* __restrict__ adj, const float* __restrict__ tmp,
                        float* __restrict__ edge_h)
{
    int kq     = blockIdx.x & 3;
    int rowblk = blockIdx.x >> 2;
    int r = rowblk * 8 + (threadIdx.x >> 5);
    int c = threadIdx.x & 31;
    float s = 0.f;
    int k0 = kq * 256;
    #pragma unroll 8
    for (int k = k0; k < k0 + 256; ++k)
        s += adj[r * 1024 + k] * tmp[k * 32 + c];
    atomicAdd(&edge_h[r * 32 + c], s);
}

// ---------------------------------------------------------------------------
extern "C" void kernel_launch(void* const* d_in, const int* in_sizes, int n_in,
                              void* d_out, int out_size, void* d_ws, size_t ws_size,
                              hipStream_t stream)
{
    const float* x   = (const float*)d_in[0];
    const int*   ei  = (const int*)  d_in[1];
    const float* ew  = (const float*)d_in[2];
    const float* ef  = (const float*)d_in[3];
    const float* adj = (const float*)d_in[4];
    const float* T   = (const float*)d_in[5];
    const float* W1  = (const float*)d_in[6];
    const float* b1  = (const float*)d_in[7];
    const float* W2  = (const float*)d_in[8];
    const float* b2  = (const float*)d_in[9];
    const float* Wn  = (const float*)d_in[10];
    const float* We  = (const float*)d_in[11];
    const float* bg  = (const float*)d_in[12];
    const float* Wc1 = (const float*)d_in[13];
    const float* bc1 = (const float*)d_in[14];
    const float* Wc2 = (const float*)d_in[15];
    const float* bc2 = (const float*)d_in[16];
    float* out = (float*)d_out;

    const int N = in_sizes[0] / 128;   // 50000
    const int E = in_sizes[1] / 2;     // 1000000
    const int* srcIdx = ei;
    const int* dstIdx = ei + E;

    float* ws     = (float*)d_ws;
    float* h1acc  = ws;                            // N*64
    float* h2acc  = h1acc + (size_t)N * 64;        // N*32
    float* nfacc  = h2acc + (size_t)N * 32;        // N*32
    float* edge_h = nfacc + (size_t)N * 32;        // 1024*32
    float* h1p    = edge_h + 1024 * 32;            // N*64
    float* h2p    = h1p   + (size_t)N * 64;        // N*32
    float* tmp    = h2p   + (size_t)N * 32;        // 1024*32
    float* nfw    = tmp   + 1024 * 32;             // N*32

    // zero the accumulators (h1acc, h2acc, nfacc, edge_h are contiguous)
    size_t zeroBytes = ((size_t)N * 64 + (size_t)N * 32 + (size_t)N * 32 + 1024 * 32) * sizeof(float);
    (void)hipMemsetAsync(d_ws, 0, zeroBytes, stream);

    const int gridRows = (N + RPB - 1) / RPB;   // 196

    // h1p = x @ W1 + b1
    gemm_k<64, 128, false><<<gridRows, 256, 0, stream>>>(
        x, W1, b1, h1p, N, 1.f, 0, nullptr, nullptr, nullptr, nullptr, nullptr, nullptr);
    // h1acc[dst] += w * h1p[src]
    scatter64_k<<<2048, 256, 0, stream>>>(h1p, srcIdx, dstIdx, ew, h1acc, E);
    // h2p = relu(h1acc) @ W2 + b2
    gemm_k<32, 64, false><<<gridRows, 256, 0, stream>>>(
        h1acc, W2, b2, h2p, N, 1.f, 1, nullptr, nullptr, nullptr, nullptr, nullptr, nullptr);
    // h2acc[dst] += w * h2p[src]
    scatter32_k<true, false><<<2048, 256, 0, stream>>>(h2p, srcIdx, dstIdx, ew, h2acc, E);
    // nfacc[dst] += relu(h2acc[src])
    scatter32_k<false, true><<<2048, 256, 0, stream>>>(h2acc, srcIdx, dstIdx, nullptr, nfacc, E);
    // tmp = edge_features @ We ; edge_h = adj_e @ tmp
    efwe_k<<<128, 256, 0, stream>>>(ef, We, tmp);
    adjmm_k<<<512, 256, 0, stream>>>(adj, tmp, edge_h);
    // nfw = (nfacc / E) @ Wn
    gemm_k<32, 32, false><<<gridRows, 256, 0, stream>>>(
        nfacc, Wn, nullptr, nfw, N, 1.f / (float)E, 0,
        nullptr, nullptr, nullptr, nullptr, nullptr, nullptr);
    // out = softmax(classifier(relu(T@edge_h + nfw + bg)))
    gemm_k<32, 1024, true><<<gridRows, 256, 0, stream>>>(
        T, edge_h, nullptr, out, N, 1.f, 0, nfw, bg, Wc1, bc1, Wc2, bc2);
}

// Round 2
// 826.336 us; speedup vs baseline: 1.2975x; 1.2975x over previous
//
#include <hip/hip_runtime.h>
#include <hip/hip_bf16.h>

#define RPB 256   // rows per block in tiled GEMM

// ---------------------------------------------------------------------------
// Tiled row-blocked GEMM (used for the three small N×K@K×C projections).
// 256 threads = 8 col-groups x 32 row-groups; 8 rows x CPT cols per thread.
// ---------------------------------------------------------------------------
template<int COLS, int K>
__global__ __launch_bounds__(256) void gemm_k(
    const float* __restrict__ X, const float* __restrict__ W,
    const float* __restrict__ bias, float* __restrict__ out,
    int nrows, float scale, int relu_in)
{
    constexpr int CPT = COLS / 8;
    constexpr int KT  = 32;
    constexpr int NKT = K / KT;

    __shared__ float sx[RPB * 36];
    __shared__ float sWT[COLS * 33];

    const int tid = threadIdx.x;
    const int cg  = tid & 7;
    const int rg  = tid >> 3;
    const int r0  = blockIdx.x * RPB;

    float acc[8][CPT];
    #pragma unroll
    for (int r = 0; r < 8; ++r)
        #pragma unroll
        for (int c = 0; c < CPT; ++c) acc[r][c] = 0.f;

    for (int kt = 0; kt < NKT; ++kt) {
        #pragma unroll
        for (int j = 0; j < 8; ++j) {
            int i  = tid + j * 256;
            int r  = i >> 3;
            int k4 = i & 7;
            int gr = r0 + r; if (gr >= nrows) gr = nrows - 1;
            float4 v = *(const float4*)&X[(size_t)gr * K + kt * KT + k4 * 4];
            if (relu_in) {
                v.x = fmaxf(v.x, 0.f); v.y = fmaxf(v.y, 0.f);
                v.z = fmaxf(v.z, 0.f); v.w = fmaxf(v.w, 0.f);
            }
            if (scale != 1.f) { v.x *= scale; v.y *= scale; v.z *= scale; v.w *= scale; }
            *(float4*)&sx[r * 36 + k4 * 4] = v;
        }
        for (int i = tid; i < COLS * KT; i += 256) {
            int kl = i / COLS, c = i % COLS;
            sWT[c * 33 + kl] = W[(size_t)(kt * KT + kl) * COLS + c];
        }
        __syncthreads();

        #pragma unroll
        for (int k4 = 0; k4 < 8; ++k4) {
            float4 a[8];
            #pragma unroll
            for (int r = 0; r < 8; ++r)
                a[r] = *(const float4*)&sx[(r * 32 + rg) * 36 + k4 * 4];
            #pragma unroll
            for (int cc = 0; cc < CPT; ++cc) {
                int c = cg * CPT + cc;
                float w0 = sWT[c * 33 + k4 * 4 + 0];
                float w1 = sWT[c * 33 + k4 * 4 + 1];
                float w2 = sWT[c * 33 + k4 * 4 + 2];
                float w3 = sWT[c * 33 + k4 * 4 + 3];
                #pragma unroll
                for (int r = 0; r < 8; ++r)
                    acc[r][cc] += a[r].x * w0 + a[r].y * w1 + a[r].z * w2 + a[r].w * w3;
            }
        }
        __syncthreads();
    }

    #pragma unroll
    for (int r = 0; r < 8; ++r) {
        int row = r0 + r * 32 + rg;
        if (row < nrows) {
            #pragma unroll
            for (int cc4 = 0; cc4 < CPT / 4; ++cc4) {
                int c = cg * CPT + cc4 * 4;
                float4 o;
                o.x = acc[r][cc4 * 4 + 0] + (bias ? bias[c + 0] : 0.f);
                o.y = acc[r][cc4 * 4 + 1] + (bias ? bias[c + 1] : 0.f);
                o.z = acc[r][cc4 * 4 + 2] + (bias ? bias[c + 2] : 0.f);
                o.w = acc[r][cc4 * 4 + 3] + (bias ? bias[c + 3] : 0.f);
                *(float4*)&out[(size_t)row * COLS + c] = o;
            }
        }
    }
}

// ---------------------------------------------------------------------------
// T-GEMM, K-split: par[kq][n][32] = T[n, kq*256:(kq+1)*256] @ eh[kslice, 32]
// grid = dim3(nrb, 4); 256 threads = 64 lanes x 4 col-groups; 4 rows x 8 cols
// per thread. LDS stride 36 (aligned float4, uniform 8 words/bank).
// ---------------------------------------------------------------------------
__global__ __launch_bounds__(256) void tgemm_k(
    const float* __restrict__ T, const float* __restrict__ eh,
    float* __restrict__ par, int nrows)
{
    __shared__ float sx[256 * 36];   // 36864 B
    __shared__ float seh[32 * 36];   //  4608 B

    const int tid  = threadIdx.x;
    const int lane = tid & 63;
    const int cg   = tid >> 6;       // 0..3
    const int r0   = blockIdx.x * 256;
    const int ks   = blockIdx.y * 256;

    float acc[4][8];
    #pragma unroll
    for (int r = 0; r < 4; ++r)
        #pragma unroll
        for (int j = 0; j < 8; ++j) acc[r][j] = 0.f;

    for (int kt = 0; kt < 8; ++kt) {
        int kb = ks + kt * 32;
        #pragma unroll
        for (int j = 0; j < 8; ++j) {
            int i  = tid + j * 256;
            int r  = i >> 3, k4 = i & 7;
            int gr = r0 + r; if (gr >= nrows) gr = nrows - 1;
            float4 v = *(const float4*)&T[(size_t)gr * 1024 + kb + k4 * 4];
            *(float4*)&sx[r * 36 + k4 * 4] = v;
        }
        #pragma unroll
        for (int j = 0; j < 4; ++j) {
            int ii = tid + j * 256;          // 0..1023
            int k = ii >> 5, c = ii & 31;
            seh[c * 36 + k] = eh[(size_t)(kb + k) * 32 + c];
        }
        __syncthreads();

        #pragma unroll
        for (int k4 = 0; k4 < 8; ++k4) {
            float4 a[4];
            #pragma unroll
            for (int r = 0; r < 4; ++r)
                a[r] = *(const float4*)&sx[(lane + r * 64) * 36 + k4 * 4];
            #pragma unroll
            for (int jj = 0; jj < 8; ++jj) {
                float4 w = *(const float4*)&seh[(cg * 8 + jj) * 36 + k4 * 4];
                #pragma unroll
                for (int r = 0; r < 4; ++r)
                    acc[r][jj] += a[r].x * w.x + a[r].y * w.y
                                + a[r].z * w.z + a[r].w * w.w;
            }
        }
        __syncthreads();
    }

    float* p = par + (size_t)blockIdx.y * nrows * 32;
    #pragma unroll
    for (int r = 0; r < 4; ++r) {
        int row = r0 + lane + r * 64;
        if (row < nrows) {
            float4 o0 = make_float4(acc[r][0], acc[r][1], acc[r][2], acc[r][3]);
            float4 o1 = make_float4(acc[r][4], acc[r][5], acc[r][6], acc[r][7]);
            *(float4*)&p[(size_t)row * 32 + cg * 8]     = o0;
            *(float4*)&p[(size_t)row * 32 + cg * 8 + 4] = o1;
        }
    }
}

// ---------------------------------------------------------------------------
// Epilogue: shared = relu(sum_kq par + nfw + bg); classifier; softmax.
// ---------------------------------------------------------------------------
__global__ __launch_bounds__(256) void classify_k(
    const float* __restrict__ par, const float* __restrict__ nfw,
    const float* __restrict__ bg, const float* __restrict__ Wc1,
    const float* __restrict__ bc1, const float* __restrict__ Wc2,
    const float* __restrict__ bc2, float* __restrict__ out, int nrows)
{
    __shared__ float sWc1T[1024];   // [j_out][i_in]
    __shared__ float sWc2[64];
    __shared__ float sb[66];        // bc1[0:32], bg[32:64], bc2[64:66]

    int tid = threadIdx.x;
    for (int i = tid; i < 1024; i += 256)
        sWc1T[(i & 31) * 32 + (i >> 5)] = Wc1[i];
    if (tid < 64) sWc2[tid] = Wc2[tid];
    if (tid < 32)      sb[tid] = bc1[tid];
    else if (tid < 64) sb[tid] = bg[tid - 32];
    else if (tid < 66) sb[tid] = bc2[tid - 64];
    __syncthreads();

    int row = blockIdx.x * 256 + tid;
    if (row >= nrows) return;

    size_t stride = (size_t)nrows * 32;
    float4 sh4[8];
    #pragma unroll
    for (int i4 = 0; i4 < 8; ++i4) {
        const float* base = par + (size_t)row * 32 + i4 * 4;
        float4 v0 = *(const float4*)(base);
        float4 v1 = *(const float4*)(base + stride);
        float4 v2 = *(const float4*)(base + 2 * stride);
        float4 v3 = *(const float4*)(base + 3 * stride);
        float4 nf = *(const float4*)&nfw[(size_t)row * 32 + i4 * 4];
        float4 o;
        o.x = fmaxf(v0.x + v1.x + v2.x + v3.x + nf.x + sb[32 + i4 * 4 + 0], 0.f);
        o.y = fmaxf(v0.y + v1.y + v2.y + v3.y + nf.y + sb[32 + i4 * 4 + 1], 0.f);
        o.z = fmaxf(v0.z + v1.z + v2.z + v3.z + nf.z + sb[32 + i4 * 4 + 2], 0.f);
        o.w = fmaxf(v0.w + v1.w + v2.w + v3.w + nf.w + sb[32 + i4 * 4 + 3], 0.f);
        sh4[i4] = o;
    }

    float l0 = sb[64], l1 = sb[65];
    #pragma unroll
    for (int jj = 0; jj < 32; ++jj) {
        float s = sb[jj];
        #pragma unroll
        for (int i4 = 0; i4 < 8; ++i4) {
            float4 w4 = *(const float4*)&sWc1T[jj * 32 + i4 * 4];
            s += sh4[i4].x * w4.x + sh4[i4].y * w4.y
               + sh4[i4].z * w4.z + sh4[i4].w * w4.w;
        }
        s = fmaxf(s, 0.f);
        l0 += s * sWc2[jj * 2 + 0];
        l1 += s * sWc2[jj * 2 + 1];
    }
    float p0 = 1.f / (1.f + expf(l1 - l0));
    float p1 = 1.f / (1.f + expf(l0 - l1));
    *(float2*)&out[(size_t)row * 2] = make_float2(p0, p1);
}

// --------------------------- CSR construction ------------------------------
__global__ void hist_k(const int* __restrict__ dst, int* __restrict__ deg, int E)
{
    int e = blockIdx.x * 256 + threadIdx.x;
    if (e < E) atomicAdd(&deg[dst[e]], 1);
}

__global__ void scan1_k(const int* __restrict__ deg, int* __restrict__ bsum, int N)
{
    __shared__ int s[256];
    int t = threadIdx.x, i = blockIdx.x * 256 + t;
    s[t] = (i < N) ? deg[i] : 0;
    __syncthreads();
    for (int off = 128; off > 0; off >>= 1) {
        if (t < off) s[t] += s[t + off];
        __syncthreads();
    }
    if (t == 0) bsum[blockIdx.x] = s[0];
}

__global__ void scan2_k(const int* __restrict__ bsum, int* __restrict__ boff,
                        int NB, int* __restrict__ rsN)
{
    if (threadIdx.x == 0 && blockIdx.x == 0) {
        int acc = 0;
        for (int b = 0; b < NB; ++b) { boff[b] = acc; acc += bsum[b]; }
        *rsN = acc;   // row_start[N] = E
    }
}

__global__ void scan3_k(const int* __restrict__ deg, const int* __restrict__ boff,
                        int* __restrict__ rs, int* __restrict__ cur, int N)
{
    __shared__ int s[256];
    int t = threadIdx.x, i = blockIdx.x * 256 + t;
    int v = (i < N) ? deg[i] : 0;
    s[t] = v;
    __syncthreads();
    for (int off = 1; off < 256; off <<= 1) {
        int u = (t >= off) ? s[t - off] : 0;
        __syncthreads();
        s[t] += u;
        __syncthreads();
    }
    if (i < N) {
        int ex = boff[blockIdx.x] + s[t] - v;
        rs[i] = ex;
        cur[i] = ex;
    }
}

__global__ void fill_k(const int* __restrict__ src, const int* __restrict__ dst,
                       const float* __restrict__ ew, int* __restrict__ cur,
                       int* __restrict__ esrc, float* __restrict__ ews, int E)
{
    int e = blockIdx.x * 256 + threadIdx.x;
    if (e < E) {
        int pos = atomicAdd(&cur[dst[e]], 1);
        esrc[pos] = src[e];
        ews[pos]  = ew[e];
    }
}

// --------------------------- CSR gathers -----------------------------------
// Wave per node; 4 edge-slots x 16 float4 feature chunks per instruction.
__global__ __launch_bounds__(256) void gather64_k(
    const float* __restrict__ hp, const int* __restrict__ esrc,
    const float* __restrict__ ews, const int* __restrict__ rs,
    float* __restrict__ outv, int N)
{
    int lane = threadIdx.x & 63;
    int sub  = lane >> 4;            // edge slot 0..3
    int ch   = lane & 15;            // float4 chunk 0..15
    int wid  = (blockIdx.x * blockDim.x + threadIdx.x) >> 6;
    int nw   = (gridDim.x * blockDim.x) >> 6;
    for (int n = wid; n < N; n += nw) {
        int j0 = rs[n], j1 = rs[n + 1];
        float4 acc = make_float4(0.f, 0.f, 0.f, 0.f);
        for (int j = j0; j < j1; j += 4) {
            int je = j + sub;
            bool valid = je < j1;
            int idx = valid ? je : j0;
            int s = esrc[idx];
            float w = ews[idx];
            if (!valid) w = 0.f;
            float4 v = *(const float4*)&hp[(size_t)s * 64 + ch * 4];
            acc.x += v.x * w; acc.y += v.y * w;
            acc.z += v.z * w; acc.w += v.w * w;
        }
        acc.x += __shfl_xor(acc.x, 16); acc.y += __shfl_xor(acc.y, 16);
        acc.z += __shfl_xor(acc.z, 16); acc.w += __shfl_xor(acc.w, 16);
        acc.x += __shfl_xor(acc.x, 32); acc.y += __shfl_xor(acc.y, 32);
        acc.z += __shfl_xor(acc.z, 32); acc.w += __shfl_xor(acc.w, 32);
        if (lane < 16)
            *(float4*)&outv[(size_t)n * 64 + ch * 4] = acc;
    }
}

// Wave per node; 8 edge-slots x 8 float4 chunks.
template<bool WEIGHTED, bool RELU>
__global__ __launch_bounds__(256) void gather32_k(
    const float* __restrict__ hp, const int* __restrict__ esrc,
    const float* __restrict__ ews, const int* __restrict__ rs,
    float* __restrict__ outv, int N)
{
    int lane = threadIdx.x & 63;
    int sub  = lane >> 3;            // edge slot 0..7
    int ch   = lane & 7;             // float4 chunk 0..7
    int wid  = (blockIdx.x * blockDim.x + threadIdx.x) >> 6;
    int nw   = (gridDim.x * blockDim.x) >> 6;
    for (int n = wid; n < N; n += nw) {
        int j0 = rs[n], j1 = rs[n + 1];
        float4 acc = make_float4(0.f, 0.f, 0.f, 0.f);
        for (int j = j0; j < j1; j += 8) {
            int je = j + sub;
            bool valid = je < j1;
            int idx = valid ? je : j0;
            int s = esrc[idx];
            float w = WEIGHTED ? ews[idx] : 1.f;
            if (!valid) w = 0.f;
            float4 v = *(const float4*)&hp[(size_t)s * 32 + ch * 4];
            if (RELU) {
                v.x = fmaxf(v.x, 0.f); v.y = fmaxf(v.y, 0.f);
                v.z = fmaxf(v.z, 0.f); v.w = fmaxf(v.w, 0.f);
            }
            acc.x += v.x * w; acc.y += v.y * w;
            acc.z += v.z * w; acc.w += v.w * w;
        }
        acc.x += __shfl_xor(acc.x, 8);  acc.y += __shfl_xor(acc.y, 8);
        acc.z += __shfl_xor(acc.z, 8);  acc.w += __shfl_xor(acc.w, 8);
        acc.x += __shfl_xor(acc.x, 16); acc.y += __shfl_xor(acc.y, 16);
        acc.z += __shfl_xor(acc.z, 16); acc.w += __shfl_xor(acc.w, 16);
        acc.x += __shfl_xor(acc.x, 32); acc.y += __shfl_xor(acc.y, 32);
        acc.z += __shfl_xor(acc.z, 32); acc.w += __shfl_xor(acc.w, 32);
        if (lane < 8)
            *(float4*)&outv[(size_t)n * 32 + ch * 4] = acc;
    }
}

// ----------------------- small edge-side matmuls ---------------------------
__global__ void efwe_k(const float* __restrict__ ef, const float* __restrict__ We,
                       float* __restrict__ tmp)
{
    int idx = blockIdx.x * 256 + threadIdx.x;
    int row = idx >> 5, c = idx & 31;
    float s = 0.f;
    #pragma unroll
    for (int k = 0; k < 64; ++k)
        s += ef[row * 64 + k] * We[k * 32 + c];
    tmp[row * 32 + c] = s;
}

__global__ void adjmm_k(const float* __restrict__ adj, const float* __restrict__ tmp,
                        float* __restrict__ edge_h)
{
    int kq     = blockIdx.x & 3;
    int rowblk = blockIdx.x >> 2;
    int r = rowblk * 8 + (threadIdx.x >> 5);
    int c = threadIdx.x & 31;
    float s = 0.f;
    int k0 = kq * 256;
    #pragma unroll 8
    for (int k = k0; k < k0 + 256; ++k)
        s += adj[r * 1024 + k] * tmp[k * 32 + c];
    atomicAdd(&edge_h[r * 32 + c], s);
}

// ---------------------------------------------------------------------------
extern "C" void kernel_launch(void* const* d_in, const int* in_sizes, int n_in,
                              void* d_out, int out_size, void* d_ws, size_t ws_size,
                              hipStream_t stream)
{
    const float* x   = (const float*)d_in[0];
    const int*   ei  = (const int*)  d_in[1];
    const float* ew  = (const float*)d_in[2];
    const float* ef  = (const float*)d_in[3];
    const float* adj = (const float*)d_in[4];
    const float* T   = (const float*)d_in[5];
    const float* W1  = (const float*)d_in[6];
    const float* b1  = (const float*)d_in[7];
    const float* W2  = (const float*)d_in[8];
    const float* b2  = (const float*)d_in[9];
    const float* Wn  = (const float*)d_in[10];
    const float* We  = (const float*)d_in[11];
    const float* bg  = (const float*)d_in[12];
    const float* Wc1 = (const float*)d_in[13];
    const float* bc1 = (const float*)d_in[14];
    const float* Wc2 = (const float*)d_in[15];
    const float* bc2 = (const float*)d_in[16];
    float* out = (float*)d_out;

    const int N = in_sizes[0] / 128;   // 50000
    const int E = in_sizes[1] / 2;     // 1000000
    const int* srcIdx = ei;
    const int* dstIdx = ei + E;

    // ---- workspace layout (floats) ----
    float* ws = (float*)d_ws;
    size_t o = 0;
    float* h1acc  = ws + o; o += (size_t)N * 64;
    float* h2acc  = ws + o; o += (size_t)N * 32;
    float* nfacc  = ws + o; o += (size_t)N * 32;
    float* edge_h = ws + o; o += 1024 * 32;
    float* tmp    = ws + o; o += 1024 * 32;
    float* nfw    = ws + o; o += (size_t)N * 32;
    float* par    = ws + o; o += (size_t)N * 128;  // also aliases h1p/h2p
    float* h1p    = par;                           // [N,64] dead before tgemm
    float* h2p    = par + (size_t)N * 64;          // [N,32] dead before tgemm
    int*   esrc   = (int*)(ws + o);   o += E;
    float* ews    = ws + o;           o += E;
    int*   deg    = (int*)(ws + o);   o += N;
    int*   rs     = (int*)(ws + o);   o += N + 1;
    int*   cur    = (int*)(ws + o);   o += N + 1;
    int*   bsum   = (int*)(ws + o);   o += 256;
    int*   boff   = (int*)(ws + o);   o += 256;

    const int NB = (N + 255) / 256;   // 196

    // zero only what must be zero: deg + edge_h (adjmm accumulates atomically)
    (void)hipMemsetAsync(deg, 0, (size_t)N * sizeof(int), stream);
    (void)hipMemsetAsync(edge_h, 0, 1024 * 32 * sizeof(float), stream);

    // 1. h1p = x @ W1 + b1
    gemm_k<64, 128><<<NB, 256, 0, stream>>>(x, W1, b1, h1p, N, 1.f, 0);

    // 2. CSR build
    hist_k<<<(E + 255) / 256, 256, 0, stream>>>(dstIdx, deg, E);
    scan1_k<<<NB, 256, 0, stream>>>(deg, bsum, N);
    scan2_k<<<1, 64, 0, stream>>>(bsum, boff, NB, rs + N);
    scan3_k<<<NB, 256, 0, stream>>>(deg, boff, rs, cur, N);
    fill_k<<<(E + 255) / 256, 256, 0, stream>>>(srcIdx, dstIdx, ew, cur, esrc, ews, E);

    // 3. h1acc[n] = sum_{e: dst=n} w_e * h1p[src_e]
    gather64_k<<<1024, 256, 0, stream>>>(h1p, esrc, ews, rs, h1acc, N);

    // 4. h2p = relu(h1acc) @ W2 + b2
    gemm_k<32, 64><<<NB, 256, 0, stream>>>(h1acc, W2, b2, h2p, N, 1.f, 1);

    // 5. h2acc[n] = sum w_e * h2p[src_e]
    gather32_k<true, false><<<1024, 256, 0, stream>>>(h2p, esrc, ews, rs, h2acc, N);

    // 6. nfacc[n] = sum relu(h2acc)[src_e]
    gather32_k<false, true><<<1024, 256, 0, stream>>>(h2acc, esrc, ews, rs, nfacc, N);

    // 7. edge_h = adj_e @ (ef @ We)
    efwe_k<<<128, 256, 0, stream>>>(ef, We, tmp);
    adjmm_k<<<512, 256, 0, stream>>>(adj, tmp, edge_h);

    // 8. nfw = (nfacc / E) @ Wn
    gemm_k<32, 32><<<NB, 256, 0, stream>>>(nfacc, Wn, nullptr, nfw, N, 1.f / (float)E, 0);

    // 9. par[kq] = T[:, kq*256:+256] @ edge_h[kslice]
    tgemm_k<<<dim3(NB, 4), 256, 0, stream>>>(T, edge_h, par, N);

    // 10. out = softmax(classifier(relu(sum par + nfw + bg)))
    classify_k<<<NB, 256, 0, stream>>>(par, nfw, bg, Wc1, bc1, Wc2, bc2, out, N);
}

// Round 3
// 745.635 us; speedup vs baseline: 1.4379x; 1.1082x over previous
//
#include <hip/hip_runtime.h>
#include <hip/hip_bf16.h>

#define RPB 256   // rows per block in tiled GEMM

// ---------------------------------------------------------------------------
// Tiled row-blocked GEMM (used for the three small N×K@K×C projections).
// 256 threads = 8 col-groups x 32 row-groups; 8 rows x CPT cols per thread.
// ---------------------------------------------------------------------------
template<int COLS, int K>
__global__ __launch_bounds__(256) void gemm_k(
    const float* __restrict__ X, const float* __restrict__ W,
    const float* __restrict__ bias, float* __restrict__ out,
    int nrows, float scale, int relu_in)
{
    constexpr int CPT = COLS / 8;
    constexpr int KT  = 32;
    constexpr int NKT = K / KT;

    __shared__ float sx[RPB * 36];
    __shared__ float sWT[COLS * 33];

    const int tid = threadIdx.x;
    const int cg  = tid & 7;
    const int rg  = tid >> 3;
    const int r0  = blockIdx.x * RPB;

    float acc[8][CPT];
    #pragma unroll
    for (int r = 0; r < 8; ++r)
        #pragma unroll
        for (int c = 0; c < CPT; ++c) acc[r][c] = 0.f;

    for (int kt = 0; kt < NKT; ++kt) {
        #pragma unroll
        for (int j = 0; j < 8; ++j) {
            int i  = tid + j * 256;
            int r  = i >> 3;
            int k4 = i & 7;
            int gr = r0 + r; if (gr >= nrows) gr = nrows - 1;
            float4 v = *(const float4*)&X[(size_t)gr * K + kt * KT + k4 * 4];
            if (relu_in) {
                v.x = fmaxf(v.x, 0.f); v.y = fmaxf(v.y, 0.f);
                v.z = fmaxf(v.z, 0.f); v.w = fmaxf(v.w, 0.f);
            }
            if (scale != 1.f) { v.x *= scale; v.y *= scale; v.z *= scale; v.w *= scale; }
            *(float4*)&sx[r * 36 + k4 * 4] = v;
        }
        for (int i = tid; i < COLS * KT; i += 256) {
            int kl = i / COLS, c = i % COLS;
            sWT[c * 33 + kl] = W[(size_t)(kt * KT + kl) * COLS + c];
        }
        __syncthreads();

        #pragma unroll
        for (int k4 = 0; k4 < 8; ++k4) {
            float4 a[8];
            #pragma unroll
            for (int r = 0; r < 8; ++r)
                a[r] = *(const float4*)&sx[(r * 32 + rg) * 36 + k4 * 4];
            #pragma unroll
            for (int cc = 0; cc < CPT; ++cc) {
                int c = cg * CPT + cc;
                float w0 = sWT[c * 33 + k4 * 4 + 0];
                float w1 = sWT[c * 33 + k4 * 4 + 1];
                float w2 = sWT[c * 33 + k4 * 4 + 2];
                float w3 = sWT[c * 33 + k4 * 4 + 3];
                #pragma unroll
                for (int r = 0; r < 8; ++r)
                    acc[r][cc] += a[r].x * w0 + a[r].y * w1 + a[r].z * w2 + a[r].w * w3;
            }
        }
        __syncthreads();
    }

    #pragma unroll
    for (int r = 0; r < 8; ++r) {
        int row = r0 + r * 32 + rg;
        if (row < nrows) {
            #pragma unroll
            for (int cc4 = 0; cc4 < CPT / 4; ++cc4) {
                int c = cg * CPT + cc4 * 4;
                float4 o;
                o.x = acc[r][cc4 * 4 + 0] + (bias ? bias[c + 0] : 0.f);
                o.y = acc[r][cc4 * 4 + 1] + (bias ? bias[c + 1] : 0.f);
                o.z = acc[r][cc4 * 4 + 2] + (bias ? bias[c + 2] : 0.f);
                o.w = acc[r][cc4 * 4 + 3] + (bias ? bias[c + 3] : 0.f);
                *(float4*)&out[(size_t)row * COLS + c] = o;
            }
        }
    }
}

// ---------------------------------------------------------------------------
// T-GEMM v3: par[kq][n][32] = T[n, kq*256:+256] @ eh[kslice, 32]
// Thread = one row, all 32 cols in regs. eh slice staged ONCE in LDS
// (broadcast reads, no conflicts); T streamed global->VGPR, one 128B line
// per thread per 32-k chunk, software-pipelined. No barriers in K-loop.
// ---------------------------------------------------------------------------
__global__ __launch_bounds__(256, 4) void tgemm2_k(
    const float* __restrict__ T, const float* __restrict__ eh,
    float* __restrict__ par, int nrows)
{
    __shared__ float seh[256 * 32];   // 32 KB: eh[ks+k][c]
    const int tid = threadIdx.x;
    const int ks  = blockIdx.y * 256;

    #pragma unroll
    for (int j = 0; j < 8; ++j) {
        int i = tid + j * 256;        // float4 index 0..2047
        *(float4*)&seh[i * 4] = *(const float4*)&eh[(size_t)ks * 32 + (size_t)i * 4];
    }
    __syncthreads();

    int row = blockIdx.x * 256 + tid;
    int r   = row < nrows ? row : nrows - 1;
    const float* Tp = T + (size_t)r * 1024 + ks;

    float acc[32];
    #pragma unroll
    for (int c = 0; c < 32; ++c) acc[c] = 0.f;

    float4 t[8];
    #pragma unroll
    for (int q = 0; q < 8; ++q) t[q] = *(const float4*)&Tp[q * 4];

    for (int kc = 0; kc < 8; ++kc) {
        float4 tn[8];
        if (kc < 7) {
            #pragma unroll
            for (int q = 0; q < 8; ++q)
                tn[q] = *(const float4*)&Tp[(kc + 1) * 32 + q * 4];
        }
        #pragma unroll
        for (int q = 0; q < 8; ++q) {
            #pragma unroll
            for (int j = 0; j < 4; ++j) {
                float a = (j == 0) ? t[q].x : (j == 1) ? t[q].y : (j == 2) ? t[q].z : t[q].w;
                int k = kc * 32 + q * 4 + j;
                #pragma unroll
                for (int c4 = 0; c4 < 8; ++c4) {
                    float4 w = *(const float4*)&seh[k * 32 + c4 * 4];
                    acc[c4 * 4 + 0] += a * w.x;
                    acc[c4 * 4 + 1] += a * w.y;
                    acc[c4 * 4 + 2] += a * w.z;
                    acc[c4 * 4 + 3] += a * w.w;
                }
            }
        }
        #pragma unroll
        for (int q = 0; q < 8; ++q) t[q] = tn[q];
    }

    if (row < nrows) {
        float* p = par + (size_t)blockIdx.y * nrows * 32 + (size_t)row * 32;
        #pragma unroll
        for (int c4 = 0; c4 < 8; ++c4)
            *(float4*)&p[c4 * 4] = make_float4(acc[c4 * 4 + 0], acc[c4 * 4 + 1],
                                               acc[c4 * 4 + 2], acc[c4 * 4 + 3]);
    }
}

// ---------------------------------------------------------------------------
// Epilogue: shared = relu(sum_kq par + nfw + bg); classifier; softmax.
// ---------------------------------------------------------------------------
__global__ __launch_bounds__(256) void classify_k(
    const float* __restrict__ par, const float* __restrict__ nfw,
    const float* __restrict__ bg, const float* __restrict__ Wc1,
    const float* __restrict__ bc1, const float* __restrict__ Wc2,
    const float* __restrict__ bc2, float* __restrict__ out, int nrows)
{
    __shared__ float sWc1T[1024];   // [j_out][i_in]
    __shared__ float sWc2[64];
    __shared__ float sb[66];        // bc1[0:32], bg[32:64], bc2[64:66]

    int tid = threadIdx.x;
    for (int i = tid; i < 1024; i += 256)
        sWc1T[(i & 31) * 32 + (i >> 5)] = Wc1[i];
    if (tid < 64) sWc2[tid] = Wc2[tid];
    if (tid < 32)      sb[tid] = bc1[tid];
    else if (tid < 64) sb[tid] = bg[tid - 32];
    else if (tid < 66) sb[tid] = bc2[tid - 64];
    __syncthreads();

    int row = blockIdx.x * 256 + tid;
    if (row >= nrows) return;

    size_t stride = (size_t)nrows * 32;
    float4 sh4[8];
    #pragma unroll
    for (int i4 = 0; i4 < 8; ++i4) {
        const float* base = par + (size_t)row * 32 + i4 * 4;
        float4 v0 = *(const float4*)(base);
        float4 v1 = *(const float4*)(base + stride);
        float4 v2 = *(const float4*)(base + 2 * stride);
        float4 v3 = *(const float4*)(base + 3 * stride);
        float4 nf = *(const float4*)&nfw[(size_t)row * 32 + i4 * 4];
        float4 o;
        o.x = fmaxf(v0.x + v1.x + v2.x + v3.x + nf.x + sb[32 + i4 * 4 + 0], 0.f);
        o.y = fmaxf(v0.y + v1.y + v2.y + v3.y + nf.y + sb[32 + i4 * 4 + 1], 0.f);
        o.z = fmaxf(v0.z + v1.z + v2.z + v3.z + nf.z + sb[32 + i4 * 4 + 2], 0.f);
        o.w = fmaxf(v0.w + v1.w + v2.w + v3.w + nf.w + sb[32 + i4 * 4 + 3], 0.f);
        sh4[i4] = o;
    }

    float l0 = sb[64], l1 = sb[65];
    #pragma unroll
    for (int jj = 0; jj < 32; ++jj) {
        float s = sb[jj];
        #pragma unroll
        for (int i4 = 0; i4 < 8; ++i4) {
            float4 w4 = *(const float4*)&sWc1T[jj * 32 + i4 * 4];
            s += sh4[i4].x * w4.x + sh4[i4].y * w4.y
               + sh4[i4].z * w4.z + sh4[i4].w * w4.w;
        }
        s = fmaxf(s, 0.f);
        l0 += s * sWc2[jj * 2 + 0];
        l1 += s * sWc2[jj * 2 + 1];
    }
    float p0 = 1.f / (1.f + expf(l1 - l0));
    float p1 = 1.f / (1.f + expf(l0 - l1));
    *(float2*)&out[(size_t)row * 2] = make_float2(p0, p1);
}

// --------------------------- CSR construction ------------------------------
__global__ void hist_k(const int* __restrict__ dst, int* __restrict__ deg, int E)
{
    int e = blockIdx.x * 256 + threadIdx.x;
    if (e < E) atomicAdd(&deg[dst[e]], 1);
}

__global__ void scan1_k(const int* __restrict__ deg, int* __restrict__ bsum, int N)
{
    __shared__ int s[256];
    int t = threadIdx.x, i = blockIdx.x * 256 + t;
    s[t] = (i < N) ? deg[i] : 0;
    __syncthreads();
    for (int off = 128; off > 0; off >>= 1) {
        if (t < off) s[t] += s[t + off];
        __syncthreads();
    }
    if (t == 0) bsum[blockIdx.x] = s[0];
}

// parallel single-block scan over block sums (NB <= 256)
__global__ void scan2_k(const int* __restrict__ bsum, int* __restrict__ boff,
                        int NB, int* __restrict__ rsN)
{
    __shared__ int s[256];
    int t = threadIdx.x;
    int v = (t < NB) ? bsum[t] : 0;
    s[t] = v;
    __syncthreads();
    for (int off = 1; off < 256; off <<= 1) {
        int u = (t >= off) ? s[t - off] : 0;
        __syncthreads();
        s[t] += u;
        __syncthreads();
    }
    if (t < NB) boff[t] = s[t] - v;        // exclusive prefix
    if (t == NB - 1) *rsN = s[t];          // total = E
}

__global__ void scan3_k(const int* __restrict__ deg, const int* __restrict__ boff,
                        int* __restrict__ rs, int* __restrict__ cur, int N)
{
    __shared__ int s[256];
    int t = threadIdx.x, i = blockIdx.x * 256 + t;
    int v = (i < N) ? deg[i] : 0;
    s[t] = v;
    __syncthreads();
    for (int off = 1; off < 256; off <<= 1) {
        int u = (t >= off) ? s[t - off] : 0;
        __syncthreads();
        s[t] += u;
        __syncthreads();
    }
    if (i < N) {
        int ex = boff[blockIdx.x] + s[t] - v;
        rs[i] = ex;
        cur[i] = ex;
    }
}

__global__ void fill_k(const int* __restrict__ src, const int* __restrict__ dst,
                       const float* __restrict__ ew, int* __restrict__ cur,
                       int* __restrict__ esrc, float* __restrict__ ews, int E)
{
    int e = blockIdx.x * 256 + threadIdx.x;
    if (e < E) {
        int pos = atomicAdd(&cur[dst[e]], 1);
        esrc[pos] = src[e];
        ews[pos]  = ew[e];
    }
}

// --------------------------- CSR gathers -----------------------------------
// Wave per node; 2x4 edge-slots in flight x 16 float4 feature chunks.
__global__ __launch_bounds__(256) void gather64_k(
    const float* __restrict__ hp, const int* __restrict__ esrc,
    const float* __restrict__ ews, const int* __restrict__ rs,
    float* __restrict__ outv, int N)
{
    int lane = threadIdx.x & 63;
    int sub  = lane >> 4;            // edge slot 0..3
    int ch   = lane & 15;            // float4 chunk 0..15
    int wid  = (blockIdx.x * blockDim.x + threadIdx.x) >> 6;
    int nw   = (gridDim.x * blockDim.x) >> 6;
    for (int n = wid; n < N; n += nw) {
        int j0 = rs[n], j1 = rs[n + 1];
        float4 acc = make_float4(0.f, 0.f, 0.f, 0.f);
        for (int j = j0; j < j1; j += 8) {
            int ja = j + sub, jb = j + 4 + sub;
            bool va = ja < j1, vb = jb < j1;
            int ia = va ? ja : j0, ib = vb ? jb : j0;
            int sa = esrc[ia], sb2 = esrc[ib];
            float wa = va ? ews[ia] : 0.f;
            float wb = vb ? ews[ib] : 0.f;
            float4 v1 = *(const float4*)&hp[(size_t)sa * 64 + ch * 4];
            float4 v2 = *(const float4*)&hp[(size_t)sb2 * 64 + ch * 4];
            acc.x += v1.x * wa + v2.x * wb;
            acc.y += v1.y * wa + v2.y * wb;
            acc.z += v1.z * wa + v2.z * wb;
            acc.w += v1.w * wa + v2.w * wb;
        }
        acc.x += __shfl_xor(acc.x, 16); acc.y += __shfl_xor(acc.y, 16);
        acc.z += __shfl_xor(acc.z, 16); acc.w += __shfl_xor(acc.w, 16);
        acc.x += __shfl_xor(acc.x, 32); acc.y += __shfl_xor(acc.y, 32);
        acc.z += __shfl_xor(acc.z, 32); acc.w += __shfl_xor(acc.w, 32);
        if (lane < 16)
            *(float4*)&outv[(size_t)n * 64 + ch * 4] = acc;
    }
}

// Wave per node; 2x8 edge-slots in flight x 8 float4 chunks.
template<bool WEIGHTED, bool RELU>
__global__ __launch_bounds__(256) void gather32_k(
    const float* __restrict__ hp, const int* __restrict__ esrc,
    const float* __restrict__ ews, const int* __restrict__ rs,
    float* __restrict__ outv, int N)
{
    int lane = threadIdx.x & 63;
    int sub  = lane >> 3;            // edge slot 0..7
    int ch   = lane & 7;             // float4 chunk 0..7
    int wid  = (blockIdx.x * blockDim.x + threadIdx.x) >> 6;
    int nw   = (gridDim.x * blockDim.x) >> 6;
    for (int n = wid; n < N; n += nw) {
        int j0 = rs[n], j1 = rs[n + 1];
        float4 acc = make_float4(0.f, 0.f, 0.f, 0.f);
        for (int j = j0; j < j1; j += 16) {
            int ja = j + sub, jb = j + 8 + sub;
            bool va = ja < j1, vb = jb < j1;
            int ia = va ? ja : j0, ib = vb ? jb : j0;
            int sa = esrc[ia], sb2 = esrc[ib];
            float wa = WEIGHTED ? ews[ia] : 1.f;
            float wb = WEIGHTED ? ews[ib] : 1.f;
            if (!va) wa = 0.f;
            if (!vb) wb = 0.f;
            float4 v1 = *(const float4*)&hp[(size_t)sa * 32 + ch * 4];
            float4 v2 = *(const float4*)&hp[(size_t)sb2 * 32 + ch * 4];
            if (RELU) {
                v1.x = fmaxf(v1.x, 0.f); v1.y = fmaxf(v1.y, 0.f);
                v1.z = fmaxf(v1.z, 0.f); v1.w = fmaxf(v1.w, 0.f);
                v2.x = fmaxf(v2.x, 0.f); v2.y = fmaxf(v2.y, 0.f);
                v2.z = fmaxf(v2.z, 0.f); v2.w = fmaxf(v2.w, 0.f);
            }
            acc.x += v1.x * wa + v2.x * wb;
            acc.y += v1.y * wa + v2.y * wb;
            acc.z += v1.z * wa + v2.z * wb;
            acc.w += v1.w * wa + v2.w * wb;
        }
        acc.x += __shfl_xor(acc.x, 8);  acc.y += __shfl_xor(acc.y, 8);
        acc.z += __shfl_xor(acc.z, 8);  acc.w += __shfl_xor(acc.w, 8);
        acc.x += __shfl_xor(acc.x, 16); acc.y += __shfl_xor(acc.y, 16);
        acc.z += __shfl_xor(acc.z, 16); acc.w += __shfl_xor(acc.w, 16);
        acc.x += __shfl_xor(acc.x, 32); acc.y += __shfl_xor(acc.y, 32);
        acc.z += __shfl_xor(acc.z, 32); acc.w += __shfl_xor(acc.w, 32);
        if (lane < 8)
            *(float4*)&outv[(size_t)n * 32 + ch * 4] = acc;
    }
}

// ----------------------- small edge-side matmuls ---------------------------
__global__ void efwe_k(const float* __restrict__ ef, const float* __restrict__ We,
                       float* __restrict__ tmp)
{
    int idx = blockIdx.x * 256 + threadIdx.x;
    int row = idx >> 5, c = idx & 31;
    float s = 0.f;
    #pragma unroll
    for (int k = 0; k < 64; ++k)
        s += ef[row * 64 + k] * We[k * 32 + c];
    tmp[row * 32 + c] = s;
}

__global__ void adjmm_k(const float* __restrict__ adj, const float* __restrict__ tmp,
                        float* __restrict__ edge_h)
{
    int kq     = blockIdx.x & 3;
    int rowblk = blockIdx.x >> 2;
    int r = rowblk * 8 + (threadIdx.x >> 5);
    int c = threadIdx.x & 31;
    float s = 0.f;
    int k0 = kq * 256;
    #pragma unroll 8
    for (int k = k0; k < k0 + 256; ++k)
        s += adj[r * 1024 + k] * tmp[k * 32 + c];
    atomicAdd(&edge_h[r * 32 + c], s);
}

// ---------------------------------------------------------------------------
extern "C" void kernel_launch(void* const* d_in, const int* in_sizes, int n_in,
                              void* d_out, int out_size, void* d_ws, size_t ws_size,
                              hipStream_t stream)
{
    const float* x   = (const float*)d_in[0];
    const int*   ei  = (const int*)  d_in[1];
    const float* ew  = (const float*)d_in[2];
    const float* ef  = (const float*)d_in[3];
    const float* adj = (const float*)d_in[4];
    const float* T   = (const float*)d_in[5];
    const float* W1  = (const float*)d_in[6];
    const float* b1  = (const float*)d_in[7];
    const float* W2  = (const float*)d_in[8];
    const float* b2  = (const float*)d_in[9];
    const float* Wn  = (const float*)d_in[10];
    const float* We  = (const float*)d_in[11];
    const float* bg  = (const float*)d_in[12];
    const float* Wc1 = (const float*)d_in[13];
    const float* bc1 = (const float*)d_in[14];
    const float* Wc2 = (const float*)d_in[15];
    const float* bc2 = (const float*)d_in[16];
    float* out = (float*)d_out;

    const int N = in_sizes[0] / 128;   // 50000
    const int E = in_sizes[1] / 2;     // 1000000
    const int* srcIdx = ei;
    const int* dstIdx = ei + E;

    // ---- workspace layout (floats) ----
    float* ws = (float*)d_ws;
    size_t o = 0;
    float* h1acc  = ws + o; o += (size_t)N * 64;
    float* h2acc  = ws + o; o += (size_t)N * 32;
    float* nfacc  = ws + o; o += (size_t)N * 32;
    float* edge_h = ws + o; o += 1024 * 32;
    float* tmp    = ws + o; o += 1024 * 32;
    float* nfw    = ws + o; o += (size_t)N * 32;
    float* par    = ws + o; o += (size_t)N * 128;  // also aliases h1p/h2p
    float* h1p    = par;                           // [N,64] dead before tgemm
    float* h2p    = par + (size_t)N * 64;          // [N,32] dead before tgemm
    int*   esrc   = (int*)(ws + o);   o += E;
    float* ews    = ws + o;           o += E;
    int*   deg    = (int*)(ws + o);   o += N;
    int*   rs     = (int*)(ws + o);   o += N + 1;
    int*   cur    = (int*)(ws + o);   o += N + 1;
    int*   bsum   = (int*)(ws + o);   o += 256;
    int*   boff   = (int*)(ws + o);   o += 256;

    const int NB = (N + 255) / 256;   // 196

    // zero only what must be zero: deg + edge_h (adjmm accumulates atomically)
    (void)hipMemsetAsync(deg, 0, (size_t)N * sizeof(int), stream);
    (void)hipMemsetAsync(edge_h, 0, 1024 * 32 * sizeof(float), stream);

    // 1. h1p = x @ W1 + b1
    gemm_k<64, 128><<<NB, 256, 0, stream>>>(x, W1, b1, h1p, N, 1.f, 0);

    // 2. CSR build
    hist_k<<<(E + 255) / 256, 256, 0, stream>>>(dstIdx, deg, E);
    scan1_k<<<NB, 256, 0, stream>>>(deg, bsum, N);
    scan2_k<<<1, 256, 0, stream>>>(bsum, boff, NB, rs + N);
    scan3_k<<<NB, 256, 0, stream>>>(deg, boff, rs, cur, N);
    fill_k<<<(E + 255) / 256, 256, 0, stream>>>(srcIdx, dstIdx, ew, cur, esrc, ews, E);

    // 3. h1acc[n] = sum_{e: dst=n} w_e * h1p[src_e]
    gather64_k<<<1024, 256, 0, stream>>>(h1p, esrc, ews, rs, h1acc, N);

    // 4. h2p = relu(h1acc) @ W2 + b2
    gemm_k<32, 64><<<NB, 256, 0, stream>>>(h1acc, W2, b2, h2p, N, 1.f, 1);

    // 5. h2acc[n] = sum w_e * h2p[src_e]
    gather32_k<true, false><<<1024, 256, 0, stream>>>(h2p, esrc, ews, rs, h2acc, N);

    // 6. nfacc[n] = sum relu(h2acc)[src_e]
    gather32_k<false, true><<<1024, 256, 0, stream>>>(h2acc, esrc, ews, rs, nfacc, N);

    // 7. edge_h = adj_e @ (ef @ We)
    efwe_k<<<128, 256, 0, stream>>>(ef, We, tmp);
    adjmm_k<<<512, 256, 0, stream>>>(adj, tmp, edge_h);

    // 8. nfw = (nfacc / E) @ Wn
    gemm_k<32, 32><<<NB, 256, 0, stream>>>(nfacc, Wn, nullptr, nfw, N, 1.f / (float)E, 0);

    // 9. par[kq] = T[:, kq*256:+256] @ edge_h[kslice]  (streaming, no barriers)
    tgemm2_k<<<dim3(NB, 4), 256, 0, stream>>>(T, edge_h, par, N);

    // 10. out = softmax(classifier(relu(sum par + nfw + bg)))
    classify_k<<<NB, 256, 0, stream>>>(par, nfw, bg, Wc1, bc1, Wc2, bc2, out, N);
}